// Round 1
// baseline (378.855 us; speedup 1.0000x reference)
//
#include <hip/hip_runtime.h>

#define BB 32
#define TXX 4096
#define DD 512

// ---------------------------------------------------------------------------
// Kernel 1: mask-format detect + per-batch count + write alpha output.
// alpha[b,t] = use_masking ? (mask[b,t] ? 1/count_b : 0) : 1.0
// The softmax over a size-1 axis in the reference makes alpha==1 pre-mask,
// so nothing else (Wa/Wh/Wc/V/tanh) affects the output.
// ---------------------------------------------------------------------------
__global__ __launch_bounds__(256) void k_alpha(const void* __restrict__ mask_raw,
                                               const int* __restrict__ use_masking_p,
                                               float* __restrict__ alpha_out)
{
    __shared__ int s_has_f, s_has_odd;
    __shared__ float s_red[256];
    const int b = blockIdx.x;
    const int tid = threadIdx.x;

    // ---- mask dtype probe over first 256 dwords (valid in all encodings) ----
    if (tid == 0) { s_has_f = 0; s_has_odd = 0; }
    __syncthreads();
    {
        unsigned int w = ((const unsigned int*)mask_raw)[tid];
        if (w == 0x3F800000u) atomicOr(&s_has_f, 1);       // float32 1.0f
        else if (w > 1u)      atomicOr(&s_has_odd, 1);     // packed 0/1 bytes
    }
    __syncthreads();
    const int fmt = s_has_f ? 2 : (s_has_odd ? 1 : 0);     // 2=f32, 1=byte, 0=int32
    const int use_masking = (use_masking_p[0] != 0);

    const unsigned char* mb = (const unsigned char*)mask_raw;
    const int*           mi = (const int*)mask_raw;
    const float*         mf = (const float*)mask_raw;

    // ---- count over TX (16 per thread) ----
    bool m[16];
    float cnt = 0.f;
    #pragma unroll
    for (int k = 0; k < 16; ++k) {
        const int t = b * TXX + tid + k * 256;
        bool mm;
        if (fmt == 1)      mm = (mb[t] != 0);
        else if (fmt == 0) mm = (mi[t] != 0);
        else               mm = (mf[t] != 0.f);
        m[k] = mm;
        cnt += mm ? 1.f : 0.f;
    }
    s_red[tid] = cnt;
    __syncthreads();
    for (int s = 128; s > 0; s >>= 1) {
        if (tid < s) s_red[tid] += s_red[tid + s];
        __syncthreads();
    }
    const float inv = use_masking ? (1.f / s_red[0]) : 1.f;

    // ---- write alpha ----
    #pragma unroll
    for (int k = 0; k < 16; ++k) {
        const int t = tid + k * 256;
        float w = use_masking ? (m[k] ? inv : 0.f) : 1.f;
        alpha_out[b * TXX + t] = w;
    }
}

// ---------------------------------------------------------------------------
// Kernel 2: partial context sums. Block = (tc, b); 256 threads.
// Threads 0..127 cover D=512 via float4 (coalesced 2 KiB/row); tsub = tid>>7
// interleaves two t-rows. w is wave-uniform per row -> skip loads when w==0
// (halves HBM traffic for ~50% masks).
// ---------------------------------------------------------------------------
__global__ __launch_bounds__(256) void k_partial(const float* __restrict__ a,
                                                 const float* __restrict__ alpha,
                                                 float4* __restrict__ part,
                                                 int tc_count)
{
    const int b    = blockIdx.y;
    const int tc   = blockIdx.x;
    const int tid  = threadIdx.x;
    const int d4   = tid & 127;
    const int tsub = tid >> 7;
    const int tchunk = TXX / tc_count;

    const float4* a4 = (const float4*)(a + (size_t)b * TXX * DD);
    const float*  al = alpha + (size_t)b * TXX;

    float4 acc = {0.f, 0.f, 0.f, 0.f};
    const int t0 = tc * tchunk;
    #pragma unroll 4
    for (int tt = tsub; tt < tchunk; tt += 2) {
        const int t = t0 + tt;
        const float w = al[t];
        if (w != 0.f) {                         // wave-uniform branch
            float4 v = a4[(size_t)t * (DD / 4) + d4];
            acc.x += w * v.x; acc.y += w * v.y;
            acc.z += w * v.z; acc.w += w * v.w;
        }
    }

    __shared__ float4 s_acc[128];
    if (tsub == 1) s_acc[d4] = acc;
    __syncthreads();
    if (tsub == 0) {
        float4 o = s_acc[d4];
        acc.x += o.x; acc.y += o.y; acc.z += o.z; acc.w += o.w;
        part[((size_t)b * tc_count + tc) * 128 + d4] = acc;
    }
}

// ---------------------------------------------------------------------------
// Kernel 3: reduce partials -> context [B,1,D] at d_out[0 .. B*D).
// ---------------------------------------------------------------------------
__global__ __launch_bounds__(256) void k_reduce(const float4* __restrict__ part,
                                                float4* __restrict__ ctx,
                                                int tc_count)
{
    const int gid = blockIdx.x * 256 + threadIdx.x;   // 0 .. B*128-1
    const int b   = gid >> 7;
    const int d4  = gid & 127;
    float4 acc = {0.f, 0.f, 0.f, 0.f};
    for (int tc = 0; tc < tc_count; ++tc) {
        float4 v = part[((size_t)b * tc_count + tc) * 128 + d4];
        acc.x += v.x; acc.y += v.y; acc.z += v.z; acc.w += v.w;
    }
    ctx[gid] = acc;
}

extern "C" void kernel_launch(void* const* d_in, const int* in_sizes, int n_in,
                              void* d_out, int out_size, void* d_ws, size_t ws_size,
                              hipStream_t stream) {
    const float* a          = (const float*)d_in[0];
    const void*  mask       = d_in[3];
    const int*   use_mask_p = (const int*)d_in[9];

    float* out   = (float*)d_out;
    float* alpha = out + BB * DD;          // outputs: context [B*D] then alpha [B*TX]

    // pick largest power-of-two tc_count that fits ws (needs B*tc*128*16 bytes)
    int tc_count = 32;
    while (tc_count > 1 && (size_t)BB * tc_count * 128 * 16 > ws_size) tc_count >>= 1;

    k_alpha  <<<BB, 256, 0, stream>>>(mask, use_mask_p, alpha);
    k_partial<<<dim3(tc_count, BB), 256, 0, stream>>>(a, alpha, (float4*)d_ws, tc_count);
    k_reduce <<<(BB * 128) / 256, 256, 0, stream>>>((const float4*)d_ws, (float4*)out, tc_count);
}

// Round 2
// 360.624 us; speedup vs baseline: 1.0506x; 1.0506x over previous
//
#include <hip/hip_runtime.h>

#define BB 32
#define TXX 4096
#define DD 512

// ---------------------------------------------------------------------------
// Kernel 1: mask-format detect + per-batch count + write alpha output.
// alpha[b,t] = use_masking ? (mask[b,t] ? 1/count_b : 0) : 1.0
// (softmax over the size-1 last axis == all-ones, so Wa/Wh/Wc/V/tanh are dead)
// ---------------------------------------------------------------------------
__global__ __launch_bounds__(256) void k_alpha(const void* __restrict__ mask_raw,
                                               const int* __restrict__ use_masking_p,
                                               float* __restrict__ alpha_out)
{
    __shared__ int s_has_f, s_has_odd;
    __shared__ float s_red[256];
    const int b = blockIdx.x;
    const int tid = threadIdx.x;

    if (tid == 0) { s_has_f = 0; s_has_odd = 0; }
    __syncthreads();
    {
        unsigned int w = ((const unsigned int*)mask_raw)[tid];
        if (w == 0x3F800000u) atomicOr(&s_has_f, 1);       // float32 1.0f
        else if (w > 1u)      atomicOr(&s_has_odd, 1);     // packed 0/1 bytes
    }
    __syncthreads();
    const int fmt = s_has_f ? 2 : (s_has_odd ? 1 : 0);     // 2=f32, 1=byte, 0=int32
    const int use_masking = (use_masking_p[0] != 0);

    const unsigned char* mb = (const unsigned char*)mask_raw;
    const int*           mi = (const int*)mask_raw;
    const float*         mf = (const float*)mask_raw;

    bool m[16];
    float cnt = 0.f;
    #pragma unroll
    for (int k = 0; k < 16; ++k) {
        const int t = b * TXX + tid + k * 256;
        bool mm;
        if (fmt == 1)      mm = (mb[t] != 0);
        else if (fmt == 0) mm = (mi[t] != 0);
        else               mm = (mf[t] != 0.f);
        m[k] = mm;
        cnt += mm ? 1.f : 0.f;
    }
    s_red[tid] = cnt;
    __syncthreads();
    for (int s = 128; s > 0; s >>= 1) {
        if (tid < s) s_red[tid] += s_red[tid + s];
        __syncthreads();
    }
    const float inv = use_masking ? (1.f / s_red[0]) : 1.f;

    #pragma unroll
    for (int k = 0; k < 16; ++k) {
        const int t = tid + k * 256;
        float w = use_masking ? (m[k] ? inv : 0.f) : 1.f;
        alpha_out[b * TXX + t] = w;
    }
}

// ---------------------------------------------------------------------------
// Kernel 2: compact-then-sum partial context.
// Phase A: threads 0..tchunk-1 read alpha for this chunk, ballot+prefix-sum
//          compact nonzero rows (idx, w) into LDS.
// Phase B: dense branch-free loop over the compacted list — weights from LDS,
//          row loads fully independent -> software-pipelines cleanly.
// Block 256 thr: d4 = tid&127 covers D=512 via float4; tsub = tid>>7
// interleaves two list entries.
// ---------------------------------------------------------------------------
__global__ __launch_bounds__(256) void k_partial(const float* __restrict__ a,
                                                 const float* __restrict__ alpha,
                                                 float4* __restrict__ part,
                                                 int tc_count)
{
    const int b    = blockIdx.y;
    const int tc   = blockIdx.x;
    const int tid  = threadIdx.x;
    const int d4   = tid & 127;
    const int tsub = tid >> 7;
    const int tchunk = TXX / tc_count;          // 128 at tc_count=32 (<=256 required)
    const int t0 = tc * tchunk;

    __shared__ float          s_w[256];
    __shared__ unsigned short s_idx[256];
    __shared__ int            s_wtot[4];        // per-wave nonzero counts
    __shared__ float4         s_acc[128];

    const float* al = alpha + (size_t)b * TXX;

    // ---- Phase A: compaction ----
    {
        const int lane = tid & 63;
        const int wave = tid >> 6;
        float w = 0.f;
        bool p = false;
        if (tid < tchunk) { w = al[t0 + tid]; p = (w != 0.f); }
        unsigned long long bal = __ballot(p);
        int lpfx = __popcll(bal & ((lane == 0) ? 0ull : (~0ull >> (64 - lane))));
        if (lane == 0) s_wtot[wave] = __popcll(bal);
        __syncthreads();
        int woff = 0;
        for (int i = 0; i < wave; ++i) woff += s_wtot[i];
        if (p) {
            int pos = woff + lpfx;
            s_idx[pos] = (unsigned short)tid;
            s_w[pos]   = w;
        }
        __syncthreads();
    }
    const int n = s_wtot[0] + s_wtot[1] + s_wtot[2] + s_wtot[3];

    // ---- Phase B: dense weighted sum over compacted list ----
    const float4* a4 = (const float4*)(a + (size_t)b * TXX * DD);
    float4 acc = {0.f, 0.f, 0.f, 0.f};
    #pragma unroll 4
    for (int j = tsub; j < n; j += 2) {
        const int t = t0 + s_idx[j];
        const float w = s_w[j];
        float4 v = a4[(size_t)t * (DD / 4) + d4];
        acc.x += w * v.x; acc.y += w * v.y;
        acc.z += w * v.z; acc.w += w * v.w;
    }

    if (tsub == 1) s_acc[d4] = acc;
    __syncthreads();
    if (tsub == 0) {
        float4 o = s_acc[d4];
        acc.x += o.x; acc.y += o.y; acc.z += o.z; acc.w += o.w;
        part[((size_t)b * tc_count + tc) * 128 + d4] = acc;
    }
}

// ---------------------------------------------------------------------------
// Kernel 3: reduce partials -> context [B,1,D] at d_out[0 .. B*D).
// ---------------------------------------------------------------------------
__global__ __launch_bounds__(256) void k_reduce(const float4* __restrict__ part,
                                                float4* __restrict__ ctx,
                                                int tc_count)
{
    const int gid = blockIdx.x * 256 + threadIdx.x;   // 0 .. B*128-1
    const int b   = gid >> 7;
    const int d4  = gid & 127;
    float4 acc = {0.f, 0.f, 0.f, 0.f};
    for (int tc = 0; tc < tc_count; ++tc) {
        float4 v = part[((size_t)b * tc_count + tc) * 128 + d4];
        acc.x += v.x; acc.y += v.y; acc.z += v.z; acc.w += v.w;
    }
    ctx[gid] = acc;
}

extern "C" void kernel_launch(void* const* d_in, const int* in_sizes, int n_in,
                              void* d_out, int out_size, void* d_ws, size_t ws_size,
                              hipStream_t stream) {
    const float* a          = (const float*)d_in[0];
    const void*  mask       = d_in[3];
    const int*   use_mask_p = (const int*)d_in[9];

    float* out   = (float*)d_out;
    float* alpha = out + BB * DD;          // outputs: context [B*D] then alpha [B*TX]

    // largest pow2 tc_count with tchunk<=256 and partials fitting ws
    int tc_count = 32;
    while (tc_count > 16 && (size_t)BB * tc_count * 128 * 16 > ws_size) tc_count >>= 1;

    k_alpha  <<<BB, 256, 0, stream>>>(mask, use_mask_p, alpha);
    k_partial<<<dim3(tc_count, BB), 256, 0, stream>>>(a, alpha, (float4*)d_ws, tc_count);
    k_reduce <<<(BB * 128) / 256, 256, 0, stream>>>((const float4*)d_ws, (float4*)out, tc_count);
}

// Round 3
// 352.107 us; speedup vs baseline: 1.0760x; 1.0242x over previous
//
#include <hip/hip_runtime.h>

#define BB 32
#define TXX 4096
#define DD 512
#define TC 32                 // chunks per batch
#define TCHUNK (TXX / TC)     // 128 rows per block

// ---------------------------------------------------------------------------
// Fused kernel: per-batch mask count + alpha write + compacted partial sum.
// Softmax over the size-1 last axis == all-ones, so Wa/Wh/Wc/V/tanh are dead:
//   alpha[b,t] = use_masking ? (mask ? 1/count_b : 0) : 1
//   context[b,:] = sum_t alpha[b,t] * a[b,t,:]
// Nonzero weight is UNIFORM (inv) -> sum selected rows, scale once at end.
// Grid (TC, BB), 256 threads. Each block:
//   Phase 0: count batch-b mask (16 KB slice, L2-resident across blocks)
//   Phase A: write alpha for its 128-row chunk, ballot-compact nonzero rows
//   Phase B: dense branch-free float4 sum over compacted list
// ---------------------------------------------------------------------------
__global__ __launch_bounds__(256) void k_main(const float* __restrict__ a,
                                              const void* __restrict__ mask_raw,
                                              const int* __restrict__ use_masking_p,
                                              float* __restrict__ alpha_out,
                                              float4* __restrict__ part)
{
    const int b    = blockIdx.y;
    const int tc   = blockIdx.x;
    const int tid  = threadIdx.x;
    const int lane = tid & 63;
    const int wave = tid >> 6;

    __shared__ int            s_has_f, s_has_odd;
    __shared__ float          s_red[256];
    __shared__ unsigned short s_idx[TCHUNK];
    __shared__ int            s_wcnt[2];
    __shared__ float4         s_acc[128];

    // ---- mask dtype probe over first 256 dwords (valid in all encodings) ----
    if (tid == 0) { s_has_f = 0; s_has_odd = 0; }
    __syncthreads();
    {
        unsigned int w = ((const unsigned int*)mask_raw)[tid];
        if (w == 0x3F800000u) atomicOr(&s_has_f, 1);       // float32 1.0f
        else if (w > 1u)      atomicOr(&s_has_odd, 1);     // packed 0/1 bytes
    }
    __syncthreads();
    const int fmt = s_has_f ? 2 : (s_has_odd ? 1 : 0);     // 2=f32, 1=byte, 0=int32
    const int use_masking = (use_masking_p[0] != 0);

    const unsigned char* mb = (const unsigned char*)mask_raw;
    const int*           mi = (const int*)mask_raw;
    const float*         mf = (const float*)mask_raw;

    // ---- Phase 0: per-batch mask count (16 entries per thread) ----
    float cnt = 0.f;
    #pragma unroll
    for (int k = 0; k < 16; ++k) {
        const int t = b * TXX + tid + k * 256;
        bool mm;
        if (fmt == 1)      mm = (mb[t] != 0);
        else if (fmt == 0) mm = (mi[t] != 0);
        else               mm = (mf[t] != 0.f);
        cnt += mm ? 1.f : 0.f;
    }
    s_red[tid] = cnt;
    __syncthreads();
    for (int s = 128; s > 0; s >>= 1) {
        if (tid < s) s_red[tid] += s_red[tid + s];
        __syncthreads();
    }
    const float inv = use_masking ? (1.f / s_red[0]) : 1.f;

    // ---- Phase A: alpha write + compaction for rows [t0, t0+TCHUNK) ----
    const int t0 = tc * TCHUNK;
    bool p = false;
    if (tid < TCHUNK) {                       // waves 0,1 only (TCHUNK=128)
        const int t = b * TXX + t0 + tid;
        bool mm;
        if (fmt == 1)      mm = (mb[t] != 0);
        else if (fmt == 0) mm = (mi[t] != 0);
        else               mm = (mf[t] != 0.f);
        p = use_masking ? mm : true;
        alpha_out[(size_t)b * TXX + t0 + tid] =
            use_masking ? (mm ? inv : 0.f) : 1.f;
    }
    unsigned long long bal = __ballot(p);
    int lpfx = __popcll(bal & ((lane == 0) ? 0ull : (~0ull >> (64 - lane))));
    if (lane == 0 && wave < 2) s_wcnt[wave] = __popcll(bal);
    __syncthreads();
    if (p) {
        int pos = (wave == 1 ? s_wcnt[0] : 0) + lpfx;
        s_idx[pos] = (unsigned short)tid;
    }
    __syncthreads();
    const int n = s_wcnt[0] + s_wcnt[1];

    // ---- Phase B: dense sum over compacted list, scale once at end ----
    const int d4   = tid & 127;               // float4 column (D=512 -> 128)
    const int tsub = tid >> 7;                // interleave two list entries
    const float4* a4 = (const float4*)(a + (size_t)b * TXX * DD)
                     + (size_t)t0 * (DD / 4);
    float4 acc = {0.f, 0.f, 0.f, 0.f};
    #pragma unroll 4
    for (int j = tsub; j < n; j += 2) {
        float4 v = a4[(size_t)s_idx[j] * (DD / 4) + d4];
        acc.x += v.x; acc.y += v.y; acc.z += v.z; acc.w += v.w;
    }

    if (tsub == 1) s_acc[d4] = acc;
    __syncthreads();
    if (tsub == 0) {
        float4 o = s_acc[d4];
        acc.x = (acc.x + o.x) * inv; acc.y = (acc.y + o.y) * inv;
        acc.z = (acc.z + o.z) * inv; acc.w = (acc.w + o.w) * inv;
        part[((size_t)b * TC + tc) * 128 + d4] = acc;
    }
}

// ---------------------------------------------------------------------------
// Reduce partials -> context [B,1,D] at d_out[0 .. B*D).
// ---------------------------------------------------------------------------
__global__ __launch_bounds__(256) void k_reduce(const float4* __restrict__ part,
                                                float4* __restrict__ ctx)
{
    const int gid = blockIdx.x * 256 + threadIdx.x;   // 0 .. B*128-1
    const int b   = gid >> 7;
    const int d4  = gid & 127;
    float4 acc = {0.f, 0.f, 0.f, 0.f};
    #pragma unroll
    for (int tc = 0; tc < TC; ++tc) {
        float4 v = part[((size_t)b * TC + tc) * 128 + d4];
        acc.x += v.x; acc.y += v.y; acc.z += v.z; acc.w += v.w;
    }
    ctx[gid] = acc;
}

extern "C" void kernel_launch(void* const* d_in, const int* in_sizes, int n_in,
                              void* d_out, int out_size, void* d_ws, size_t ws_size,
                              hipStream_t stream) {
    const float* a          = (const float*)d_in[0];
    const void*  mask       = d_in[3];
    const int*   use_mask_p = (const int*)d_in[9];

    float* out   = (float*)d_out;
    float* alpha = out + BB * DD;          // outputs: context [B*D] then alpha [B*TX]

    k_main  <<<dim3(TC, BB), 256, 0, stream>>>(a, mask, use_mask_p, alpha,
                                               (float4*)d_ws);
    k_reduce<<<(BB * 128) / 256, 256, 0, stream>>>((const float4*)d_ws,
                                                   (float4*)out);
}